// Round 8
// baseline (167.409 us; speedup 1.0000x reference)
//
#include <hip/hip_runtime.h>

typedef unsigned short u16;
typedef unsigned int   u32;
typedef __attribute__((ext_vector_type(8))) short          shortx8;
typedef __attribute__((ext_vector_type(8))) unsigned short ushortx8;
typedef __attribute__((ext_vector_type(4))) float          floatx4;

#define AS1 __attribute__((address_space(1)))
#define AS3 __attribute__((address_space(3)))

#define SEG 8208   // 8192 + 16 pad cols per batch segment of Vt
#define LV  16416  // 2 * SEG

__device__ __forceinline__ float b2f(u16 v) {
  return __uint_as_float(((u32)v) << 16);
}
__device__ __forceinline__ u16 f2b(float f) {
  u32 u = __float_as_uint(f);
  u += 0x7FFF + ((u >> 16) & 1);   // RNE
  return (u16)(u >> 16);
}
__device__ __forceinline__ void cp16(const void* g, void* l) {
  // 16B/lane global->LDS DMA; LDS dest must be wave-uniform base + lane*16
  __builtin_amdgcn_global_load_lds((AS1 u32*)g, (AS3 u32*)l, 16, 0, 0);
}

// ---------------------------------------------------------------------------
// Fused prep: [0,4096) cast+width rows; [4096,4864) transpose w_qkv;
// [4864,5120) transpose w_out; [5120,5184) Vt pad-zeroing.
__global__ __launch_bounds__(256)
void prep(const float* __restrict__ x, const float* __restrict__ w_width,
          const float* __restrict__ b_width, const float* __restrict__ w_qkv,
          const float* __restrict__ w_out, u16* __restrict__ xb,
          float* __restrict__ width, u16* __restrict__ wqkvT,
          u16* __restrict__ woutT, u16* __restrict__ Vt) {
  __shared__ u16 tile[32][33];
  const int b = blockIdx.x;
  if (b < 4096) {                    // ---- cast x -> bf16, compute width
    const int lane = threadIdx.x & 63;
    const int row  = b * 4 + (threadIdx.x >> 6);
    const float* xp = x + (size_t)row * 512 + lane * 8;
    floatx4 v0 = *(const floatx4*)xp;
    floatx4 v1 = *(const floatx4*)(xp + 4);
    floatx4 w0 = *(const floatx4*)(w_width + lane * 8);
    floatx4 w1 = *(const floatx4*)(w_width + lane * 8 + 4);
    float s = 0.f;
    ushortx8 o;
#pragma unroll
    for (int j = 0; j < 4; ++j) {
      s += v0[j] * w0[j] + v1[j] * w1[j];
      o[j] = f2b(v0[j]); o[4 + j] = f2b(v1[j]);
    }
    *(ushortx8*)(xb + (size_t)row * 512 + lane * 8) = o;
#pragma unroll
    for (int m = 32; m >= 1; m >>= 1) s += __shfl_xor(s, m, 64);
    if (lane == 0)
      width[row] = 16.f / (1.f + __expf(-(s + b_width[0]))) + 1.f;
  } else if (b < 5120) {             // ---- weight transposes (fp32 -> bf16^T)
    const float* in; u16* out; int R, C, t;
    if (b < 4864) { in = w_qkv; out = wqkvT; R = 512; C = 1536; t = b - 4096; }
    else          { in = w_out; out = woutT; R = 512; C = 512;  t = b - 4864; }
    const int nbx = C / 32;
    const int cb = (t % nbx) * 32;
    const int rb = (t / nbx) * 32;
    const int tx = threadIdx.x & 31;
    const int ty = threadIdx.x >> 5;
#pragma unroll
    for (int i = 0; i < 32; i += 8)
      tile[ty + i][tx] = f2b(in[(size_t)(rb + ty + i) * C + cb + tx]);
    __syncthreads();
#pragma unroll
    for (int i = 0; i < 32; i += 8)
      out[(size_t)(cb + ty + i) * R + rb + tx] = tile[tx][ty + i];
  } else {                           // ---- Vt pad-column zeroing
    const int idx = (b - 5120) * 256 + threadIdx.x;  // 512 ch * 32 pad cols
    const int ch = idx >> 5;
    const int k  = idx & 31;
    const int seg = k >> 4;
    const int j   = k & 15;
    const int col = seg * SEG + (j < 8 ? j : 8192 + j);
    Vt[(size_t)ch * LV + col] = 0;
  }
}

// ---------------------------------------------------------------------------
// C = A[M][512] @ Bt[N][512]^T, bf16 in, fp32 acc.  128x128 tile, BK=64,
// XOR-swizzled LDS staging, LDS-shuffled coalesced epilogues.
// __launch_bounds__(256,2): waves_per_eu=4 (R7) capped the UNIFIED VGPR+AGPR
// file at 128 regs/wave -> acc(64 AGPR)+frags+addr spilled to scratch ->
// occupancy 1.8%, 135 us. At (256,2) usage is ~140 unified regs -> 3
// blocks/CU naturally, no spill (43.9 us in R4).
// MODE 1: N=1536, scatter epilogue -> Qb / Kb / Vt(transposed, batch-padded).
// MODE 2: N=512,  fp32 C (ldc=512), direct stores.
template <int MODE>
__global__ __launch_bounds__(256, 2)
void gemm_bt(const u16* __restrict__ A, const u16* __restrict__ Bt,
             void* __restrict__ C0, u16* __restrict__ Kb, u16* __restrict__ Vt) {
  const int K = 512;
  __shared__ alignas(16) u16 lds[17408];        // 34,816 B (union)
  u16* As = lds;                                // 8192 u16 (128 x 64)
  u16* Bs = lds + 8192;                         // 8192 u16
  const int tid  = threadIdx.x;
  const int lane = tid & 63;
  const int wave = tid >> 6;
  const int quad = lane >> 4;
  const int lr   = lane & 15;
  const int row0 = blockIdx.x * 128;
  const int col0 = blockIdx.y * 128;
  const int wr   = (wave >> 1) * 64;
  const int wc   = (wave & 1) * 64;

  floatx4 acc[4][4];
#pragma unroll
  for (int i = 0; i < 4; ++i)
#pragma unroll
    for (int j = 0; j < 4; ++j) acc[i][j] = (floatx4)0.0f;

  // chunk c = p*256+tid -> LDS slot c; row c>>3, phys colblk (c&7)^(row&7)
  int srow[4], scol[4];
#pragma unroll
  for (int p = 0; p < 4; ++p) {
    int c = p * 256 + tid;
    srow[p] = c >> 3;
    scol[p] = ((c & 7) ^ (srow[p] & 7)) * 8;
  }
  const int swz = lr & 7;

  for (int k0 = 0; k0 < K; k0 += 64) {
#pragma unroll
    for (int p = 0; p < 4; ++p)
      cp16(A + (size_t)(row0 + srow[p]) * K + k0 + scol[p], &As[(p * 256 + tid) * 8]);
#pragma unroll
    for (int p = 0; p < 4; ++p)
      cp16(Bt + (size_t)(col0 + srow[p]) * K + k0 + scol[p], &Bs[(p * 256 + tid) * 8]);
    __syncthreads();

#pragma unroll
    for (int ks = 0; ks < 2; ++ks) {
      shortx8 af[4], bf[4];
#pragma unroll
      for (int mi = 0; mi < 4; ++mi)
        af[mi] = *(const shortx8*)
            &As[((wr + mi * 16 + lr) * 8 + ((ks * 4 + quad) ^ swz)) * 8];
#pragma unroll
      for (int ni = 0; ni < 4; ++ni)
        bf[ni] = *(const shortx8*)
            &Bs[((wc + ni * 16 + lr) * 8 + ((ks * 4 + quad) ^ swz)) * 8];
#pragma unroll
      for (int mi = 0; mi < 4; ++mi)
#pragma unroll
        for (int ni = 0; ni < 4; ++ni)
          acc[mi][ni] = __builtin_amdgcn_mfma_f32_16x16x32_bf16(
              af[mi], bf[ni], acc[mi][ni], 0, 0, 0);
    }
    __syncthreads();
  }

  // C/D layout: col = lane&15, row = quad*4 + reg  [verified m89/m91]
  if constexpr (MODE == 1) {
    if (col0 < 1024) {               // ---- Q or K: row-major LDS, coalesced out
      u16* dst = (col0 < 512) ? (u16*)C0 : Kb;
      const int cb = col0 & 511;
#pragma unroll
      for (int mi = 0; mi < 4; ++mi)
#pragma unroll
        for (int ni = 0; ni < 4; ++ni)
#pragma unroll
          for (int r = 0; r < 4; ++r)
            lds[(wr + mi * 16 + quad * 4 + r) * 136 + wc + ni * 16 + lr] =
                f2b(acc[mi][ni][r]);
      __syncthreads();
      const int rr = tid >> 4, cc = (tid & 15) * 8;
#pragma unroll
      for (int it = 0; it < 8; ++it) {
        int row = it * 16 + rr;
        *(ushortx8*)(dst + (size_t)(row0 + row) * 512 + cb + cc) =
            *(const ushortx8*)&lds[row * 136 + cc];
      }
    } else {                         // ---- V: transposed LDS, coalesced out
      const int cb = col0 - 1024;
      const int bb = row0 >> 13, pib0 = row0 & 8191;
#pragma unroll
      for (int mi = 0; mi < 4; ++mi)
#pragma unroll
        for (int ni = 0; ni < 4; ++ni)
#pragma unroll
          for (int r = 0; r < 4; ++r)
            lds[(wc + ni * 16 + lr) * 136 + wr + mi * 16 + quad * 4 + r] =
                f2b(acc[mi][ni][r]);
      __syncthreads();
      const int rr = tid >> 4, cc = (tid & 15) * 8;
#pragma unroll
      for (int it = 0; it < 8; ++it) {
        int chl = it * 16 + rr;
        ushortx8 v = *(const ushortx8*)&lds[chl * 136 + cc];
        *(ushortx8*)(Vt + (size_t)(cb + chl) * LV + (size_t)bb * SEG + 8 + pib0 + cc) = v;
      }
    }
  } else {
    float* Cf = (float*)C0;
#pragma unroll
    for (int mi = 0; mi < 4; ++mi)
#pragma unroll
      for (int ni = 0; ni < 4; ++ni)
#pragma unroll
        for (int r = 0; r < 4; ++r) {
          int row = row0 + wr + mi * 16 + quad * 4 + r;
          int col = col0 + wc + ni * 16 + lr;
          Cf[(size_t)row * 512 + col] = acc[mi][ni][r];
        }
  }
}

// ---------------------------------------------------------------------------
// MFMA local attention, per-wave tiles. Block = 16 positions, 4 waves.
// Each wave: FULL 16x32 score tile over all K=512 channels, private softmax,
// per-wave P, PV on its own 128-channel chunk, padded-LDS coalesced flush.
__global__ __launch_bounds__(256)
void attn_mfma(const u16* __restrict__ Q, const u16* __restrict__ Kb,
               const u16* __restrict__ Vt, const float* __restrict__ width,
               u16* __restrict__ Out) {
  __shared__ u16 P[4][16][40];      // pad 40: 16B-aligned rows, ~2-way banks
  __shared__ u16 O[4][16][136];     // pad 136: conflict-free flush
  const int tid  = threadIdx.x;
  const int lane = tid & 63;
  const int wave = tid >> 6;
  const int quad = lane >> 4;
  const int lr   = lane & 15;
  const int p0   = blockIdx.x * 16;
  const int pib0 = p0 & 8191;
  const int bb   = p0 >> 13;

  // ---- Phase A: full 16x32 scores (B-frags: K rows p0-8+lr and p0+8+lr)
  floatx4 s0 = (floatx4)0.0f, s1 = (floatx4)0.0f;
#pragma unroll
  for (int s = 0; s < 16; ++s) {    // 16 * 32 = K=512
    const int k0 = s * 32 + quad * 8;
    shortx8 af = *(const shortx8*)(Q  + (size_t)(p0 + lr) * 512 + k0);
    shortx8 f0 = *(const shortx8*)(Kb + (ptrdiff_t)(p0 - 8 + lr) * 512 + k0);
    shortx8 f1 = *(const shortx8*)(Kb + (ptrdiff_t)(p0 + 8 + lr) * 512 + k0);
    s0 = __builtin_amdgcn_mfma_f32_16x16x32_bf16(af, f0, s0, 0, 0, 0);
    s1 = __builtin_amdgcn_mfma_f32_16x16x32_bf16(af, f1, s1, 0, 0, 0);
  }

  // ---- per-lane softmax over rows m = quad*4+r, cols j=lr (s0) / lr+16 (s1)
  const float scale = 0.044194173824159216f;   // 512^-0.5
  float v0[4], v1[4], mx[4];
#pragma unroll
  for (int r = 0; r < 4; ++r) {
    const int row = quad * 4 + r;
    const float wrow = width[p0 + row];
    // col j = lr
    {
      const int d  = lr - row;
      const int jb = pib0 + lr - 8;
      const bool inband  = (d >= 0);                 // d <= 15 < 16 always
      const bool inbatch = ((unsigned)jb < 8192u);
      float rel  = fabsf((float)(d - 8));
      float mask = 1.f / (1.f + __expf(-5.f * (wrow - rel)));
      float pen  = (1.f - mask) * 10000.f;
      v0[r] = inband ? ((inbatch ? s0[r] * scale : 0.f) - pen) : -1e30f;
    }
    // col j = lr + 16
    {
      const int d  = lr + 16 - row;
      const int jb = pib0 + lr + 8;
      const bool inband  = (d <= 16);                // d >= 1 > 0 always
      const bool inbatch = ((unsigned)jb < 8192u);
      float rel  = fabsf((float)(d - 8));
      float mask = 1.f / (1.f + __expf(-5.f * (wrow - rel)));
      float pen  = (1.f - mask) * 10000.f;
      v1[r] = inband ? ((inbatch ? s1[r] * scale : 0.f) - pen) : -1e30f;
    }
    mx[r] = fmaxf(v0[r], v1[r]);
  }
#pragma unroll
  for (int m = 8; m >= 1; m >>= 1)
#pragma unroll
    for (int r = 0; r < 4; ++r) mx[r] = fmaxf(mx[r], __shfl_xor(mx[r], m, 64));
  float e0[4], e1[4], sum[4];
#pragma unroll
  for (int r = 0; r < 4; ++r) {
    e0[r] = __expf(v0[r] - mx[r]);
    e1[r] = __expf(v1[r] - mx[r]);
    sum[r] = e0[r] + e1[r];
  }
#pragma unroll
  for (int m = 8; m >= 1; m >>= 1)
#pragma unroll
    for (int r = 0; r < 4; ++r) sum[r] += __shfl_xor(sum[r], m, 64);
#pragma unroll
  for (int r = 0; r < 4; ++r) {
    const int row = quad * 4 + r;
    const float inv = 1.f / sum[r];
    // +1 at self slot (j - row == 8) folds "+ v" into PV
    P[wave][row][lr]      = f2b(e0[r] * inv + ((lr - row) == 8 ? 1.f : 0.f));
    P[wave][row][lr + 16] = f2b(e1[r] * inv + ((lr + 16 - row) == 8 ? 1.f : 0.f));
  }
  __syncthreads();

  // ---- Phase C: PV on this wave's 128 channels
  shortx8 pf = *(const shortx8*)&P[wave][lr][quad * 8];  // A[m=lr][k=quad*8+j]
  const size_t cb0 = (size_t)bb * SEG + pib0;
#pragma unroll
  for (int ct = 0; ct < 8; ++ct) {
    const int ch = wave * 128 + ct * 16 + lr;
    shortx8 vf = *(const shortx8*)(Vt + (size_t)ch * LV + cb0 + quad * 8);
    floatx4 o = __builtin_amdgcn_mfma_f32_16x16x32_bf16(pf, vf, (floatx4)0.0f,
                                                        0, 0, 0);
#pragma unroll
    for (int r = 0; r < 4; ++r)
      O[wave][quad * 4 + r][ct * 16 + lr] = f2b(o[r]);
  }
  __syncthreads();
  {
    const int orow = lane >> 2;
#pragma unroll
    for (int i = 0; i < 4; ++i) {
      const int c = i * 32 + (lane & 3) * 8;
      ushortx8 v = *(const ushortx8*)&O[wave][orow][c];
      *(ushortx8*)(Out + (size_t)(p0 + orow) * 512 + wave * 128 + c) = v;
    }
  }
}

// ---------------------------------------------------------------------------
extern "C" void kernel_launch(void* const* d_in, const int* in_sizes, int n_in,
                              void* d_out, int out_size, void* d_ws, size_t ws_size,
                              hipStream_t stream) {
  const float* x       = (const float*)d_in[0];  // [2,8192,512] fp32
  const float* w_qkv   = (const float*)d_in[1];  // [512,1536]  fp32
  const float* w_width = (const float*)d_in[2];  // [512,1]     fp32
  const float* b_width = (const float*)d_in[3];  // [1]         fp32
  const float* w_out   = (const float*)d_in[4];  // [512,512]   fp32
  float* out = (float*)d_out;                    // [2,8192,512] fp32

  const int M = 16384, C = 512, N3 = 1536;
  char* ws = (char*)d_ws;
  u16*   xb    = (u16*)(ws);                       // 16,777,216
  u16*   Qb    = (u16*)(ws + 16777216);            // 16,777,216
  u16*   Kb    = (u16*)(ws + 33554432 + 8192);     // 8KB guard | 16.7MB | guard
  u16*   Vt    = (u16*)(ws + 50348032);            // 512*16416*2 = 16,809,984
  u16*   wqkvT = (u16*)(ws + 67158016);            //  1,572,864
  u16*   woutT = (u16*)(ws + 68730880);            //    524,288
  float* width = (float*)(ws + 69255168);          //     65,536

  dim3 blk(256);
  prep<<<dim3(5184), blk, 0, stream>>>(x, w_width, b_width, w_qkv, w_out,
                                       xb, width, wqkvT, woutT, Vt);
  gemm_bt<1><<<dim3(M / 128, N3 / 128), blk, 0, stream>>>(xb, wqkvT, Qb, Kb, Vt);
  attn_mfma<<<dim3(M / 16), blk, 0, stream>>>(Qb, Kb, Vt, width, Qb);
  gemm_bt<2><<<dim3(M / 128, C / 128), blk, 0, stream>>>(Qb, woutT, out, nullptr, nullptr);
}

// Round 9
// 162.661 us; speedup vs baseline: 1.0292x; 1.0292x over previous
//
#include <hip/hip_runtime.h>

typedef unsigned short u16;
typedef unsigned int   u32;
typedef __attribute__((ext_vector_type(8))) short          shortx8;
typedef __attribute__((ext_vector_type(8))) unsigned short ushortx8;
typedef __attribute__((ext_vector_type(4))) float          floatx4;

#define AS1 __attribute__((address_space(1)))
#define AS3 __attribute__((address_space(3)))

#define SEG 8208   // 8192 + 16 pad cols per batch segment of Vt
#define LV  16416  // 2 * SEG

__device__ __forceinline__ float b2f(u16 v) {
  return __uint_as_float(((u32)v) << 16);
}
__device__ __forceinline__ u16 f2b(float f) {
  u32 u = __float_as_uint(f);
  u += 0x7FFF + ((u >> 16) & 1);   // RNE
  return (u16)(u >> 16);
}
__device__ __forceinline__ void cp16(const void* g, void* l) {
  // 16B/lane global->LDS DMA; LDS dest must be wave-uniform base + lane*16
  __builtin_amdgcn_global_load_lds((AS1 u32*)g, (AS3 u32*)l, 16, 0, 0);
}

// ---------------------------------------------------------------------------
// Fused prep: [0,4096) cast+width rows; [4096,4864) transpose w_qkv;
// [4864,5120) transpose w_out; [5120,5184) Vt pad-zeroing.
__global__ __launch_bounds__(256)
void prep(const float* __restrict__ x, const float* __restrict__ w_width,
          const float* __restrict__ b_width, const float* __restrict__ w_qkv,
          const float* __restrict__ w_out, u16* __restrict__ xb,
          float* __restrict__ width, u16* __restrict__ wqkvT,
          u16* __restrict__ woutT, u16* __restrict__ Vt) {
  __shared__ u16 tile[32][33];
  const int b = blockIdx.x;
  if (b < 4096) {                    // ---- cast x -> bf16, compute width
    const int lane = threadIdx.x & 63;
    const int row  = b * 4 + (threadIdx.x >> 6);
    const float* xp = x + (size_t)row * 512 + lane * 8;
    floatx4 v0 = *(const floatx4*)xp;
    floatx4 v1 = *(const floatx4*)(xp + 4);
    floatx4 w0 = *(const floatx4*)(w_width + lane * 8);
    floatx4 w1 = *(const floatx4*)(w_width + lane * 8 + 4);
    float s = 0.f;
    ushortx8 o;
#pragma unroll
    for (int j = 0; j < 4; ++j) {
      s += v0[j] * w0[j] + v1[j] * w1[j];
      o[j] = f2b(v0[j]); o[4 + j] = f2b(v1[j]);
    }
    *(ushortx8*)(xb + (size_t)row * 512 + lane * 8) = o;
#pragma unroll
    for (int m = 32; m >= 1; m >>= 1) s += __shfl_xor(s, m, 64);
    if (lane == 0)
      width[row] = 16.f / (1.f + __expf(-(s + b_width[0]))) + 1.f;
  } else if (b < 5120) {             // ---- weight transposes (fp32 -> bf16^T)
    const float* in; u16* out; int R, C, t;
    if (b < 4864) { in = w_qkv; out = wqkvT; R = 512; C = 1536; t = b - 4096; }
    else          { in = w_out; out = woutT; R = 512; C = 512;  t = b - 4864; }
    const int nbx = C / 32;
    const int cb = (t % nbx) * 32;
    const int rb = (t / nbx) * 32;
    const int tx = threadIdx.x & 31;
    const int ty = threadIdx.x >> 5;
#pragma unroll
    for (int i = 0; i < 32; i += 8)
      tile[ty + i][tx] = f2b(in[(size_t)(rb + ty + i) * C + cb + tx]);
    __syncthreads();
#pragma unroll
    for (int i = 0; i < 32; i += 8)
      out[(size_t)(cb + ty + i) * R + rb + tx] = tile[tx][ty + i];
  } else {                           // ---- Vt pad-column zeroing
    const int idx = (b - 5120) * 256 + threadIdx.x;  // 512 ch * 32 pad cols
    const int ch = idx >> 5;
    const int k  = idx & 31;
    const int seg = k >> 4;
    const int j   = k & 15;
    const int col = seg * SEG + (j < 8 ? j : 8192 + j);
    Vt[(size_t)ch * LV + col] = 0;
  }
}

// ---------------------------------------------------------------------------
// C = A[M][512] @ Bt[N][512]^T, bf16 in, fp32 acc.  128x128 tile, BK=64,
// XOR-swizzled LDS staging, LDS-shuffled coalesced epilogues.
// __launch_bounds__(256,3): 3 waves/EU -> reg budget 512/3 ~= 170 unified
// regs/wave; usage ~76 VGPR + 64 AGPR = 140 fits (R7's (256,4) = 128-reg cap
// spilled -> 135 us; (256,2) left occupancy at 23% / 2 blocks/CU).
// LDS 34.8 KB x 3 blocks = 104 KB < 160 KB.
// MODE 1: N=1536, scatter epilogue -> Qb / Kb / Vt(transposed, batch-padded).
// MODE 2: N=512,  fp32 C (ldc=512), direct stores.
template <int MODE>
__global__ __launch_bounds__(256, 3)
void gemm_bt(const u16* __restrict__ A, const u16* __restrict__ Bt,
             void* __restrict__ C0, u16* __restrict__ Kb, u16* __restrict__ Vt) {
  const int K = 512;
  __shared__ alignas(16) u16 lds[17408];        // 34,816 B (union)
  u16* As = lds;                                // 8192 u16 (128 x 64)
  u16* Bs = lds + 8192;                         // 8192 u16
  const int tid  = threadIdx.x;
  const int lane = tid & 63;
  const int wave = tid >> 6;
  const int quad = lane >> 4;
  const int lr   = lane & 15;
  const int row0 = blockIdx.x * 128;
  const int col0 = blockIdx.y * 128;
  const int wr   = (wave >> 1) * 64;
  const int wc   = (wave & 1) * 64;

  floatx4 acc[4][4];
#pragma unroll
  for (int i = 0; i < 4; ++i)
#pragma unroll
    for (int j = 0; j < 4; ++j) acc[i][j] = (floatx4)0.0f;

  // chunk c = p*256+tid -> LDS slot c; row c>>3, phys colblk (c&7)^(row&7)
  int srow[4], scol[4];
#pragma unroll
  for (int p = 0; p < 4; ++p) {
    int c = p * 256 + tid;
    srow[p] = c >> 3;
    scol[p] = ((c & 7) ^ (srow[p] & 7)) * 8;
  }
  const int swz = lr & 7;

  for (int k0 = 0; k0 < K; k0 += 64) {
#pragma unroll
    for (int p = 0; p < 4; ++p)
      cp16(A + (size_t)(row0 + srow[p]) * K + k0 + scol[p], &As[(p * 256 + tid) * 8]);
#pragma unroll
    for (int p = 0; p < 4; ++p)
      cp16(Bt + (size_t)(col0 + srow[p]) * K + k0 + scol[p], &Bs[(p * 256 + tid) * 8]);
    __syncthreads();

#pragma unroll
    for (int ks = 0; ks < 2; ++ks) {
      shortx8 af[4], bf[4];
#pragma unroll
      for (int mi = 0; mi < 4; ++mi)
        af[mi] = *(const shortx8*)
            &As[((wr + mi * 16 + lr) * 8 + ((ks * 4 + quad) ^ swz)) * 8];
#pragma unroll
      for (int ni = 0; ni < 4; ++ni)
        bf[ni] = *(const shortx8*)
            &Bs[((wc + ni * 16 + lr) * 8 + ((ks * 4 + quad) ^ swz)) * 8];
#pragma unroll
      for (int mi = 0; mi < 4; ++mi)
#pragma unroll
        for (int ni = 0; ni < 4; ++ni)
          acc[mi][ni] = __builtin_amdgcn_mfma_f32_16x16x32_bf16(
              af[mi], bf[ni], acc[mi][ni], 0, 0, 0);
    }
    __syncthreads();
  }

  // C/D layout: col = lane&15, row = quad*4 + reg  [verified m89/m91]
  if constexpr (MODE == 1) {
    if (col0 < 1024) {               // ---- Q or K: row-major LDS, coalesced out
      u16* dst = (col0 < 512) ? (u16*)C0 : Kb;
      const int cb = col0 & 511;
#pragma unroll
      for (int mi = 0; mi < 4; ++mi)
#pragma unroll
        for (int ni = 0; ni < 4; ++ni)
#pragma unroll
          for (int r = 0; r < 4; ++r)
            lds[(wr + mi * 16 + quad * 4 + r) * 136 + wc + ni * 16 + lr] =
                f2b(acc[mi][ni][r]);
      __syncthreads();
      const int rr = tid >> 4, cc = (tid & 15) * 8;
#pragma unroll
      for (int it = 0; it < 8; ++it) {
        int row = it * 16 + rr;
        *(ushortx8*)(dst + (size_t)(row0 + row) * 512 + cb + cc) =
            *(const ushortx8*)&lds[row * 136 + cc];
      }
    } else {                         // ---- V: transposed LDS, coalesced out
      const int cb = col0 - 1024;
      const int bb = row0 >> 13, pib0 = row0 & 8191;
#pragma unroll
      for (int mi = 0; mi < 4; ++mi)
#pragma unroll
        for (int ni = 0; ni < 4; ++ni)
#pragma unroll
          for (int r = 0; r < 4; ++r)
            lds[(wc + ni * 16 + lr) * 136 + wr + mi * 16 + quad * 4 + r] =
                f2b(acc[mi][ni][r]);
      __syncthreads();
      const int rr = tid >> 4, cc = (tid & 15) * 8;
#pragma unroll
      for (int it = 0; it < 8; ++it) {
        int chl = it * 16 + rr;
        ushortx8 v = *(const ushortx8*)&lds[chl * 136 + cc];
        *(ushortx8*)(Vt + (size_t)(cb + chl) * LV + (size_t)bb * SEG + 8 + pib0 + cc) = v;
      }
    }
  } else {
    float* Cf = (float*)C0;
#pragma unroll
    for (int mi = 0; mi < 4; ++mi)
#pragma unroll
      for (int ni = 0; ni < 4; ++ni)
#pragma unroll
        for (int r = 0; r < 4; ++r) {
          int row = row0 + wr + mi * 16 + quad * 4 + r;
          int col = col0 + wc + ni * 16 + lr;
          Cf[(size_t)row * 512 + col] = acc[mi][ni][r];
        }
  }
}

// ---------------------------------------------------------------------------
// MFMA local attention, per-wave tiles. Block = 16 positions, 4 waves.
// Each wave: FULL 16x32 score tile over all K=512 channels, private softmax,
// per-wave P, PV on its own 128-channel chunk, padded-LDS coalesced flush.
__global__ __launch_bounds__(256)
void attn_mfma(const u16* __restrict__ Q, const u16* __restrict__ Kb,
               const u16* __restrict__ Vt, const float* __restrict__ width,
               u16* __restrict__ Out) {
  __shared__ u16 P[4][16][40];      // pad 40: 16B-aligned rows, ~2-way banks
  __shared__ u16 O[4][16][136];     // pad 136: conflict-free flush
  const int tid  = threadIdx.x;
  const int lane = tid & 63;
  const int wave = tid >> 6;
  const int quad = lane >> 4;
  const int lr   = lane & 15;
  const int p0   = blockIdx.x * 16;
  const int pib0 = p0 & 8191;
  const int bb   = p0 >> 13;

  // ---- Phase A: full 16x32 scores (B-frags: K rows p0-8+lr and p0+8+lr)
  floatx4 s0 = (floatx4)0.0f, s1 = (floatx4)0.0f;
#pragma unroll
  for (int s = 0; s < 16; ++s) {    // 16 * 32 = K=512
    const int k0 = s * 32 + quad * 8;
    shortx8 af = *(const shortx8*)(Q  + (size_t)(p0 + lr) * 512 + k0);
    shortx8 f0 = *(const shortx8*)(Kb + (ptrdiff_t)(p0 - 8 + lr) * 512 + k0);
    shortx8 f1 = *(const shortx8*)(Kb + (ptrdiff_t)(p0 + 8 + lr) * 512 + k0);
    s0 = __builtin_amdgcn_mfma_f32_16x16x32_bf16(af, f0, s0, 0, 0, 0);
    s1 = __builtin_amdgcn_mfma_f32_16x16x32_bf16(af, f1, s1, 0, 0, 0);
  }

  // ---- per-lane softmax over rows m = quad*4+r, cols j=lr (s0) / lr+16 (s1)
  const float scale = 0.044194173824159216f;   // 512^-0.5
  float v0[4], v1[4], mx[4];
#pragma unroll
  for (int r = 0; r < 4; ++r) {
    const int row = quad * 4 + r;
    const float wrow = width[p0 + row];
    // col j = lr
    {
      const int d  = lr - row;
      const int jb = pib0 + lr - 8;
      const bool inband  = (d >= 0);                 // d <= 15 < 16 always
      const bool inbatch = ((unsigned)jb < 8192u);
      float rel  = fabsf((float)(d - 8));
      float mask = 1.f / (1.f + __expf(-5.f * (wrow - rel)));
      float pen  = (1.f - mask) * 10000.f;
      v0[r] = inband ? ((inbatch ? s0[r] * scale : 0.f) - pen) : -1e30f;
    }
    // col j = lr + 16
    {
      const int d  = lr + 16 - row;
      const int jb = pib0 + lr + 8;
      const bool inband  = (d <= 16);                // d >= 1 > 0 always
      const bool inbatch = ((unsigned)jb < 8192u);
      float rel  = fabsf((float)(d - 8));
      float mask = 1.f / (1.f + __expf(-5.f * (wrow - rel)));
      float pen  = (1.f - mask) * 10000.f;
      v1[r] = inband ? ((inbatch ? s1[r] * scale : 0.f) - pen) : -1e30f;
    }
    mx[r] = fmaxf(v0[r], v1[r]);
  }
#pragma unroll
  for (int m = 8; m >= 1; m >>= 1)
#pragma unroll
    for (int r = 0; r < 4; ++r) mx[r] = fmaxf(mx[r], __shfl_xor(mx[r], m, 64));
  float e0[4], e1[4], sum[4];
#pragma unroll
  for (int r = 0; r < 4; ++r) {
    e0[r] = __expf(v0[r] - mx[r]);
    e1[r] = __expf(v1[r] - mx[r]);
    sum[r] = e0[r] + e1[r];
  }
#pragma unroll
  for (int m = 8; m >= 1; m >>= 1)
#pragma unroll
    for (int r = 0; r < 4; ++r) sum[r] += __shfl_xor(sum[r], m, 64);
#pragma unroll
  for (int r = 0; r < 4; ++r) {
    const int row = quad * 4 + r;
    const float inv = 1.f / sum[r];
    // +1 at self slot (j - row == 8) folds "+ v" into PV
    P[wave][row][lr]      = f2b(e0[r] * inv + ((lr - row) == 8 ? 1.f : 0.f));
    P[wave][row][lr + 16] = f2b(e1[r] * inv + ((lr + 16 - row) == 8 ? 1.f : 0.f));
  }
  __syncthreads();

  // ---- Phase C: PV on this wave's 128 channels
  shortx8 pf = *(const shortx8*)&P[wave][lr][quad * 8];  // A[m=lr][k=quad*8+j]
  const size_t cb0 = (size_t)bb * SEG + pib0;
#pragma unroll
  for (int ct = 0; ct < 8; ++ct) {
    const int ch = wave * 128 + ct * 16 + lr;
    shortx8 vf = *(const shortx8*)(Vt + (size_t)ch * LV + cb0 + quad * 8);
    floatx4 o = __builtin_amdgcn_mfma_f32_16x16x32_bf16(pf, vf, (floatx4)0.0f,
                                                        0, 0, 0);
#pragma unroll
    for (int r = 0; r < 4; ++r)
      O[wave][quad * 4 + r][ct * 16 + lr] = f2b(o[r]);
  }
  __syncthreads();
  {
    const int orow = lane >> 2;
#pragma unroll
    for (int i = 0; i < 4; ++i) {
      const int c = i * 32 + (lane & 3) * 8;
      ushortx8 v = *(const ushortx8*)&O[wave][orow][c];
      *(ushortx8*)(Out + (size_t)(p0 + orow) * 512 + wave * 128 + c) = v;
    }
  }
}

// ---------------------------------------------------------------------------
extern "C" void kernel_launch(void* const* d_in, const int* in_sizes, int n_in,
                              void* d_out, int out_size, void* d_ws, size_t ws_size,
                              hipStream_t stream) {
  const float* x       = (const float*)d_in[0];  // [2,8192,512] fp32
  const float* w_qkv   = (const float*)d_in[1];  // [512,1536]  fp32
  const float* w_width = (const float*)d_in[2];  // [512,1]     fp32
  const float* b_width = (const float*)d_in[3];  // [1]         fp32
  const float* w_out   = (const float*)d_in[4];  // [512,512]   fp32
  float* out = (float*)d_out;                    // [2,8192,512] fp32

  const int M = 16384, C = 512, N3 = 1536;
  char* ws = (char*)d_ws;
  u16*   xb    = (u16*)(ws);                       // 16,777,216
  u16*   Qb    = (u16*)(ws + 16777216);            // 16,777,216
  u16*   Kb    = (u16*)(ws + 33554432 + 8192);     // 8KB guard | 16.7MB | guard
  u16*   Vt    = (u16*)(ws + 50348032);            // 512*16416*2 = 16,809,984
  u16*   wqkvT = (u16*)(ws + 67158016);            //  1,572,864
  u16*   woutT = (u16*)(ws + 68730880);            //    524,288
  float* width = (float*)(ws + 69255168);          //     65,536

  dim3 blk(256);
  prep<<<dim3(5184), blk, 0, stream>>>(x, w_width, b_width, w_qkv, w_out,
                                       xb, width, wqkvT, woutT, Vt);
  gemm_bt<1><<<dim3(M / 128, N3 / 128), blk, 0, stream>>>(xb, wqkvT, Qb, Kb, Vt);
  attn_mfma<<<dim3(M / 16), blk, 0, stream>>>(Qb, Kb, Vt, width, Qb);
  gemm_bt<2><<<dim3(M / 128, C / 128), blk, 0, stream>>>(Qb, woutT, out, nullptr, nullptr);
}

// Round 10
// 151.882 us; speedup vs baseline: 1.1022x; 1.0710x over previous
//
#include <hip/hip_runtime.h>

typedef unsigned short u16;
typedef unsigned int   u32;
typedef __attribute__((ext_vector_type(8))) short          shortx8;
typedef __attribute__((ext_vector_type(8))) unsigned short ushortx8;
typedef __attribute__((ext_vector_type(4))) float          floatx4;

#define AS1 __attribute__((address_space(1)))
#define AS3 __attribute__((address_space(3)))

#define SEG 8208   // 8192 + 16 pad cols per batch segment of Vt
#define LV  16416  // 2 * SEG

__device__ __forceinline__ float b2f(u16 v) {
  return __uint_as_float(((u32)v) << 16);
}
__device__ __forceinline__ u16 f2b(float f) {
  u32 u = __float_as_uint(f);
  u += 0x7FFF + ((u >> 16) & 1);   // RNE
  return (u16)(u >> 16);
}
__device__ __forceinline__ void cp16(const void* g, void* l) {
  // 16B/lane global->LDS DMA; LDS dest must be wave-uniform base + lane*16
  __builtin_amdgcn_global_load_lds((AS1 u32*)g, (AS3 u32*)l, 16, 0, 0);
}

// ---------------------------------------------------------------------------
// Fused prep: [0,4096) cast+width rows; [4096,4864) transpose w_qkv;
// [4864,5120) transpose w_out; [5120,5184) Vt pad-zeroing.
__global__ __launch_bounds__(256)
void prep(const float* __restrict__ x, const float* __restrict__ w_width,
          const float* __restrict__ b_width, const float* __restrict__ w_qkv,
          const float* __restrict__ w_out, u16* __restrict__ xb,
          float* __restrict__ width, u16* __restrict__ wqkvT,
          u16* __restrict__ woutT, u16* __restrict__ Vt) {
  __shared__ u16 tile[32][33];
  const int b = blockIdx.x;
  if (b < 4096) {                    // ---- cast x -> bf16, compute width
    const int lane = threadIdx.x & 63;
    const int row  = b * 4 + (threadIdx.x >> 6);
    const float* xp = x + (size_t)row * 512 + lane * 8;
    floatx4 v0 = *(const floatx4*)xp;
    floatx4 v1 = *(const floatx4*)(xp + 4);
    floatx4 w0 = *(const floatx4*)(w_width + lane * 8);
    floatx4 w1 = *(const floatx4*)(w_width + lane * 8 + 4);
    float s = 0.f;
    ushortx8 o;
#pragma unroll
    for (int j = 0; j < 4; ++j) {
      s += v0[j] * w0[j] + v1[j] * w1[j];
      o[j] = f2b(v0[j]); o[4 + j] = f2b(v1[j]);
    }
    *(ushortx8*)(xb + (size_t)row * 512 + lane * 8) = o;
#pragma unroll
    for (int m = 32; m >= 1; m >>= 1) s += __shfl_xor(s, m, 64);
    if (lane == 0)
      width[row] = 16.f / (1.f + __expf(-(s + b_width[0]))) + 1.f;
  } else if (b < 5120) {             // ---- weight transposes (fp32 -> bf16^T)
    const float* in; u16* out; int R, C, t;
    if (b < 4864) { in = w_qkv; out = wqkvT; R = 512; C = 1536; t = b - 4096; }
    else          { in = w_out; out = woutT; R = 512; C = 512;  t = b - 4864; }
    const int nbx = C / 32;
    const int cb = (t % nbx) * 32;
    const int rb = (t / nbx) * 32;
    const int tx = threadIdx.x & 31;
    const int ty = threadIdx.x >> 5;
#pragma unroll
    for (int i = 0; i < 32; i += 8)
      tile[ty + i][tx] = f2b(in[(size_t)(rb + ty + i) * C + cb + tx]);
    __syncthreads();
#pragma unroll
    for (int i = 0; i < 32; i += 8)
      out[(size_t)(cb + ty + i) * R + rb + tx] = tile[tx][ty + i];
  } else {                           // ---- Vt pad-column zeroing
    const int idx = (b - 5120) * 256 + threadIdx.x;  // 512 ch * 32 pad cols
    const int ch = idx >> 5;
    const int k  = idx & 31;
    const int seg = k >> 4;
    const int j   = k & 15;
    const int col = seg * SEG + (j < 8 ? j : 8192 + j);
    Vt[(size_t)ch * LV + col] = 0;
  }
}

// ---------------------------------------------------------------------------
// C = A[M][512] @ Bt[N][512]^T, bf16 in, fp32 acc.  128x128 tile, BK=64,
// XOR-swizzled LDS staging, LDS-shuffled coalesced epilogues.
// __launch_bounds__(256,3): 170-reg/wave cap fits ~140 unified regs (R7's
// (256,4)=128-cap spilled to 135 us; (256,2) capped occupancy at 2/CU).
// MODE 1: N=1536, scatter epilogue -> Qb / Kb / Vt(transposed, batch-padded).
// MODE 2: N=512,  fp32 C (ldc=512), direct stores.
template <int MODE>
__global__ __launch_bounds__(256, 3)
void gemm_bt(const u16* __restrict__ A, const u16* __restrict__ Bt,
             void* __restrict__ C0, u16* __restrict__ Kb, u16* __restrict__ Vt) {
  const int K = 512;
  __shared__ alignas(16) u16 lds[17408];        // 34,816 B (union)
  u16* As = lds;                                // 8192 u16 (128 x 64)
  u16* Bs = lds + 8192;                         // 8192 u16
  const int tid  = threadIdx.x;
  const int lane = tid & 63;
  const int wave = tid >> 6;
  const int quad = lane >> 4;
  const int lr   = lane & 15;
  const int row0 = blockIdx.x * 128;
  const int col0 = blockIdx.y * 128;
  const int wr   = (wave >> 1) * 64;
  const int wc   = (wave & 1) * 64;

  floatx4 acc[4][4];
#pragma unroll
  for (int i = 0; i < 4; ++i)
#pragma unroll
    for (int j = 0; j < 4; ++j) acc[i][j] = (floatx4)0.0f;

  // chunk c = p*256+tid -> LDS slot c; row c>>3, phys colblk (c&7)^(row&7)
  int srow[4], scol[4];
#pragma unroll
  for (int p = 0; p < 4; ++p) {
    int c = p * 256 + tid;
    srow[p] = c >> 3;
    scol[p] = ((c & 7) ^ (srow[p] & 7)) * 8;
  }
  const int swz = lr & 7;

  for (int k0 = 0; k0 < K; k0 += 64) {
#pragma unroll
    for (int p = 0; p < 4; ++p)
      cp16(A + (size_t)(row0 + srow[p]) * K + k0 + scol[p], &As[(p * 256 + tid) * 8]);
#pragma unroll
    for (int p = 0; p < 4; ++p)
      cp16(Bt + (size_t)(col0 + srow[p]) * K + k0 + scol[p], &Bs[(p * 256 + tid) * 8]);
    __syncthreads();

#pragma unroll
    for (int ks = 0; ks < 2; ++ks) {
      shortx8 af[4], bf[4];
#pragma unroll
      for (int mi = 0; mi < 4; ++mi)
        af[mi] = *(const shortx8*)
            &As[((wr + mi * 16 + lr) * 8 + ((ks * 4 + quad) ^ swz)) * 8];
#pragma unroll
      for (int ni = 0; ni < 4; ++ni)
        bf[ni] = *(const shortx8*)
            &Bs[((wc + ni * 16 + lr) * 8 + ((ks * 4 + quad) ^ swz)) * 8];
#pragma unroll
      for (int mi = 0; mi < 4; ++mi)
#pragma unroll
        for (int ni = 0; ni < 4; ++ni)
          acc[mi][ni] = __builtin_amdgcn_mfma_f32_16x16x32_bf16(
              af[mi], bf[ni], acc[mi][ni], 0, 0, 0);
    }
    __syncthreads();
  }

  // C/D layout: col = lane&15, row = quad*4 + reg  [verified m89/m91]
  if constexpr (MODE == 1) {
    if (col0 < 1024) {               // ---- Q or K: row-major LDS, coalesced out
      u16* dst = (col0 < 512) ? (u16*)C0 : Kb;
      const int cb = col0 & 511;
#pragma unroll
      for (int mi = 0; mi < 4; ++mi)
#pragma unroll
        for (int ni = 0; ni < 4; ++ni)
#pragma unroll
          for (int r = 0; r < 4; ++r)
            lds[(wr + mi * 16 + quad * 4 + r) * 136 + wc + ni * 16 + lr] =
                f2b(acc[mi][ni][r]);
      __syncthreads();
      const int rr = tid >> 4, cc = (tid & 15) * 8;
#pragma unroll
      for (int it = 0; it < 8; ++it) {
        int row = it * 16 + rr;
        *(ushortx8*)(dst + (size_t)(row0 + row) * 512 + cb + cc) =
            *(const ushortx8*)&lds[row * 136 + cc];
      }
    } else {                         // ---- V: transposed LDS, coalesced out
      const int cb = col0 - 1024;
      const int bb = row0 >> 13, pib0 = row0 & 8191;
#pragma unroll
      for (int mi = 0; mi < 4; ++mi)
#pragma unroll
        for (int ni = 0; ni < 4; ++ni)
#pragma unroll
          for (int r = 0; r < 4; ++r)
            lds[(wc + ni * 16 + lr) * 136 + wr + mi * 16 + quad * 4 + r] =
                f2b(acc[mi][ni][r]);
      __syncthreads();
      const int rr = tid >> 4, cc = (tid & 15) * 8;
#pragma unroll
      for (int it = 0; it < 8; ++it) {
        int chl = it * 16 + rr;
        ushortx8 v = *(const ushortx8*)&lds[chl * 136 + cc];
        *(ushortx8*)(Vt + (size_t)(cb + chl) * LV + (size_t)bb * SEG + 8 + pib0 + cc) = v;
      }
    }
  } else {
    float* Cf = (float*)C0;
#pragma unroll
    for (int mi = 0; mi < 4; ++mi)
#pragma unroll
      for (int ni = 0; ni < 4; ++ni)
#pragma unroll
        for (int r = 0; r < 4; ++r) {
          int row = row0 + wr + mi * 16 + quad * 4 + r;
          int col = col0 + wc + ni * 16 + lr;
          Cf[(size_t)row * 512 + col] = acc[mi][ni][r];
        }
  }
}

// ---------------------------------------------------------------------------
// MFMA local attention, split-K (R5 structure: 1x VMEM — each wave covers a
// 128-ch slice; the R6 full-tile variant quadrupled Phase-A gather traffic).
// Phase A: partial 16x32 scores per wave -> Sp; Phase B: cross-wave reduce +
// masked softmax; Phase C: PV per 128-ch chunk; padded O flush (R6 keeper).
__global__ __launch_bounds__(256)
void attn_mfma(const u16* __restrict__ Q, const u16* __restrict__ Kb,
               const u16* __restrict__ Vt, const float* __restrict__ width,
               u16* __restrict__ Out) {
  __shared__ float Sp[8][16][16];   // [wave*2+t][row][lr]
  __shared__ u16   P[16][32];       // A-layout for PV
  __shared__ u16   O[4][16][136];   // pad 136: conflict-free flush
  const int tid  = threadIdx.x;
  const int lane = tid & 63;
  const int wave = tid >> 6;
  const int quad = lane >> 4;
  const int lr   = lane & 15;
  const int p0   = blockIdx.x * 16;
  const int pib0 = p0 & 8191;
  const int bb   = p0 >> 13;

  // ---- Phase A: partial scores over this wave's 128-channel chunk
  floatx4 s0 = (floatx4)0.0f, s1 = (floatx4)0.0f;
#pragma unroll
  for (int s = 0; s < 4; ++s) {
    const int k0 = wave * 128 + s * 32 + quad * 8;
    shortx8 af = *(const shortx8*)(Q  + (size_t)(p0 + lr) * 512 + k0);
    shortx8 f0 = *(const shortx8*)(Kb + (ptrdiff_t)(p0 - 8 + lr) * 512 + k0);
    shortx8 f1 = *(const shortx8*)(Kb + (ptrdiff_t)(p0 + 8 + lr) * 512 + k0);
    s0 = __builtin_amdgcn_mfma_f32_16x16x32_bf16(af, f0, s0, 0, 0, 0);
    s1 = __builtin_amdgcn_mfma_f32_16x16x32_bf16(af, f1, s1, 0, 0, 0);
  }
#pragma unroll
  for (int r = 0; r < 4; ++r) {
    Sp[wave * 2 + 0][quad * 4 + r][lr] = s0[r];
    Sp[wave * 2 + 1][quad * 4 + r][lr] = s1[r];
  }
  __syncthreads();

  // ---- Phase B: softmax. thread -> row=tid>>4, cols {cg, cg+16}
  {
    const int row = tid >> 4, cg = tid & 15;
    const float scale = 0.044194173824159216f;   // 512^-0.5
    const float wrow  = width[p0 + row];
    float sv[2]; float mx = -1e30f;
#pragma unroll
    for (int t = 0; t < 2; ++t) {
      const int col = t * 16 + cg;
      float s = Sp[t][row][cg] + Sp[2 + t][row][cg] +
                Sp[4 + t][row][cg] + Sp[6 + t][row][cg];
      const int d  = col - row;           // window slot 0..16 when in band
      const int jb = pib0 + col - 8;      // position within batch
      const bool inband  = (d >= 0) && (d <= 16);
      const bool inbatch = ((unsigned)jb < 8192u);
      float rel  = fabsf((float)(d - 8));
      float mask = 1.f / (1.f + __expf(-5.f * (wrow - rel)));
      float pen  = (1.f - mask) * 10000.f;
      float val  = inband ? ((inbatch ? s * scale : 0.f) - pen) : -1e30f;
      sv[t] = val;
      mx = fmaxf(mx, val);
    }
#pragma unroll
    for (int m = 8; m >= 1; m >>= 1) mx = fmaxf(mx, __shfl_xor(mx, m, 64));
    float e0 = __expf(sv[0] - mx), e1 = __expf(sv[1] - mx);
    float sum = e0 + e1;
#pragma unroll
    for (int m = 8; m >= 1; m >>= 1) sum += __shfl_xor(sum, m, 64);
    const float inv = 1.f / sum;
    // +1 at the self slot (d==8) folds the "+ v" into PV
    P[row][cg]      = f2b(e0 * inv + ((cg - row) == 8 ? 1.f : 0.f));
    P[row][cg + 16] = f2b(e1 * inv + ((cg + 16 - row) == 8 ? 1.f : 0.f));
  }
  __syncthreads();

  // ---- Phase C: PV over this wave's 128 channels
  shortx8 pf = *(const shortx8*)&P[lr][quad * 8];   // A[m=lr][k=quad*8+j]
  const size_t cb0 = (size_t)bb * SEG + pib0;       // Vt col of j_local=0
#pragma unroll
  for (int ct = 0; ct < 8; ++ct) {
    const int ch = wave * 128 + ct * 16 + lr;
    shortx8 vf = *(const shortx8*)(Vt + (size_t)ch * LV + cb0 + quad * 8);
    floatx4 o = __builtin_amdgcn_mfma_f32_16x16x32_bf16(pf, vf, (floatx4)0.0f,
                                                        0, 0, 0);
#pragma unroll
    for (int r = 0; r < 4; ++r)
      O[wave][quad * 4 + r][ct * 16 + lr] = f2b(o[r]);
  }
  __syncthreads();
  {
    const int orow = lane >> 2;
#pragma unroll
    for (int i = 0; i < 4; ++i) {
      const int c = i * 32 + (lane & 3) * 8;
      ushortx8 v = *(const ushortx8*)&O[wave][orow][c];
      *(ushortx8*)(Out + (size_t)(p0 + orow) * 512 + wave * 128 + c) = v;
    }
  }
}

// ---------------------------------------------------------------------------
extern "C" void kernel_launch(void* const* d_in, const int* in_sizes, int n_in,
                              void* d_out, int out_size, void* d_ws, size_t ws_size,
                              hipStream_t stream) {
  const float* x       = (const float*)d_in[0];  // [2,8192,512] fp32
  const float* w_qkv   = (const float*)d_in[1];  // [512,1536]  fp32
  const float* w_width = (const float*)d_in[2];  // [512,1]     fp32
  const float* b_width = (const float*)d_in[3];  // [1]         fp32
  const float* w_out   = (const float*)d_in[4];  // [512,512]   fp32
  float* out = (float*)d_out;                    // [2,8192,512] fp32

  const int M = 16384, C = 512, N3 = 1536;
  char* ws = (char*)d_ws;
  u16*   xb    = (u16*)(ws);                       // 16,777,216
  u16*   Qb    = (u16*)(ws + 16777216);            // 16,777,216
  u16*   Kb    = (u16*)(ws + 33554432 + 8192);     // 8KB guard | 16.7MB | guard
  u16*   Vt    = (u16*)(ws + 50348032);            // 512*16416*2 = 16,809,984
  u16*   wqkvT = (u16*)(ws + 67158016);            //  1,572,864
  u16*   woutT = (u16*)(ws + 68730880);            //    524,288
  float* width = (float*)(ws + 69255168);          //     65,536

  dim3 blk(256);
  prep<<<dim3(5184), blk, 0, stream>>>(x, w_width, b_width, w_qkv, w_out,
                                       xb, width, wqkvT, woutT, Vt);
  gemm_bt<1><<<dim3(M / 128, N3 / 128), blk, 0, stream>>>(xb, wqkvT, Qb, Kb, Vt);
  attn_mfma<<<dim3(M / 16), blk, 0, stream>>>(Qb, Kb, Vt, width, Qb);
  gemm_bt<2><<<dim3(M / 128, C / 128), blk, 0, stream>>>(Qb, woutT, out, nullptr, nullptr);
}